// Round 6
// baseline (58.905 us; speedup 1.0000x reference)
//
#include <hip/hip_runtime.h>

typedef short s16x8 __attribute__((ext_vector_type(8)));
typedef float f32x16 __attribute__((ext_vector_type(16)));

#define MIN3(a,b,c) fminf(fminf((a),(b)),(c))

// DIAGNOSTIC: run minpass main loop twice (idempotent) so the dispatch
// exceeds the ~40us ws-poison fills and shows up in rocprof top-5.
#define REP 2

// bf16 round-to-nearest-even helpers
__device__ __forceinline__ unsigned short rne(float f) {
    unsigned u = __float_as_uint(f);
    return (unsigned short)((u + 0x7fffu + ((u >> 16) & 1u)) >> 16);
}
__device__ __forceinline__ float b2f(unsigned short b) {
    return __uint_as_float(((unsigned)b) << 16);
}

// 16-slot hi/lo-split encoding (validated rounds 4-5, absmax 0):
//   d2 = |q|^2 + |t|^2 - 2 (qh+ql).(th+tl)
// Q: lo=[hx,hy,hz,lx,ly,lz,hx,hy]  hi=[hz,nh,nl,1,1,lx,ly,lz]
// D: lo=[-2hx,-2hy,-2hz,-2hx,-2hy,-2hz,-2lx,-2ly] hi=[-2lz,1,1,nh,nl,-2lx,-2ly,-2lz]
__device__ __forceinline__ void encD(float x, float y, float z, s16x8& lo, s16x8& hi) {
    const unsigned short hx = rne(x), hy = rne(y), hz = rne(z);
    const float fx = b2f(hx), fy = b2f(hy), fz = b2f(hz);
    const unsigned short lx = rne(x - fx), ly = rne(y - fy), lz = rne(z - fz);
    const float n = fmaf(x, x, fmaf(y, y, z * z));
    const unsigned short nh = rne(n), nl = rne(n - b2f(nh));
    const unsigned short m2hx = rne(-2.f * fx), m2hy = rne(-2.f * fy), m2hz = rne(-2.f * fz);
    const unsigned short m2lx = rne(-2.f * b2f(lx)), m2ly = rne(-2.f * b2f(ly)), m2lz = rne(-2.f * b2f(lz));
    lo[0]=(short)m2hx; lo[1]=(short)m2hy; lo[2]=(short)m2hz; lo[3]=(short)m2hx;
    lo[4]=(short)m2hy; lo[5]=(short)m2hz; lo[6]=(short)m2lx; lo[7]=(short)m2ly;
    hi[0]=(short)m2lz; hi[1]=(short)0x3f80; hi[2]=(short)0x3f80; hi[3]=(short)nh;
    hi[4]=(short)nl;   hi[5]=(short)m2lx;  hi[6]=(short)m2ly;   hi[7]=(short)m2lz;
}

__device__ __forceinline__ s16x8 encQ(float x, float y, float z, int h) {
    const unsigned short hx = rne(x), hy = rne(y), hz = rne(z);
    const float fx = b2f(hx), fy = b2f(hy), fz = b2f(hz);
    const unsigned short lx = rne(x - fx), ly = rne(y - fy), lz = rne(z - fz);
    const float n = fmaf(x, x, fmaf(y, y, z * z));
    const unsigned short nh = rne(n), nl = rne(n - b2f(nh));
    s16x8 lo, hiV;
    lo[0]=(short)hx; lo[1]=(short)hy; lo[2]=(short)hz; lo[3]=(short)lx;
    lo[4]=(short)ly; lo[5]=(short)lz; lo[6]=(short)hx; lo[7]=(short)hy;
    hiV[0]=(short)hz; hiV[1]=(short)nh; hiV[2]=(short)nl; hiV[3]=(short)0x3f80;
    hiV[4]=(short)0x3f80; hiV[5]=(short)lx; hiV[6]=(short)ly; hiV[7]=(short)lz;
    return h ? hiV : lo;
}

// ---------------------------------------------------------------------------
__global__ void __launch_bounds__(256) init_kernel(
    unsigned* __restrict__ mb, unsigned long long* __restrict__ acc,
    unsigned* __restrict__ ticket)
{
    const int i = blockIdx.x * 256 + threadIdx.x;
    mb[i] = 0x7f800000u;   // +inf
    if (i == 0) { *acc = 0ull; *ticket = 0u; }
}

// ---------------------------------------------------------------------------
// minpass (fused encode): bid fields qg(32) | split(16) | b(4) | pass(2).
// Fold-immediate structure: per t, 1 ds_read_b128 + 2 MFMA, each MFMA's 16
// acc values folded into its chain min right away (8 min3 ops / 16 values)
// -> only one f32x16 live per chain, ~85 VGPR estimate, no spill.
// No min-waves clause: let the allocator breathe (round-5 (256,4) cap is the
// prime spill suspect).
// ---------------------------------------------------------------------------
__global__ void __launch_bounds__(256) minpass(
    const float* __restrict__ pred, const float* __restrict__ tgt,
    unsigned* __restrict__ m1, unsigned* __restrict__ m2)
{
    __shared__ s16x8 sdb[16 * 64];   // [tile][half*32+pt], 16 KiB

    const int bid = blockIdx.x;
    const int qg = bid & 31, split = (bid >> 5) & 15, b = (bid >> 9) & 3, pass = bid >> 11;
    const float* __restrict__ q  = pass ? tgt : pred;
    const float* __restrict__ db = pass ? pred : tgt;
    unsigned* __restrict__ mout = pass ? m2 : m1;

    const int tid = threadIdx.x, lane = tid & 63, wid = tid >> 6;

    // stage & encode db chunk: points tid and tid+256
    {
        const float* dp = db + ((size_t)b * 8192 + split * 512 + tid) * 3;
        s16x8 lo, hi;
        encD(dp[0], dp[1], dp[2], lo, hi);
        sdb[(tid >> 5) * 64 + (tid & 31)] = lo;
        sdb[(tid >> 5) * 64 + 32 + (tid & 31)] = hi;
        const float* dp2 = dp + 768;
        encD(dp2[0], dp2[1], dp2[2], lo, hi);
        const int p = tid + 256;
        sdb[(p >> 5) * 64 + (p & 31)] = lo;
        sdb[(p >> 5) * 64 + 32 + (p & 31)] = hi;
    }

    // query fragments: 2 tiles per wave, encoded in-register
    const int tq = qg * 8 + wid * 2;
    const int h = lane >> 5;
    const float* qp = q + ((size_t)b * 8192 + tq * 32 + (lane & 31)) * 3;
    const s16x8 aq0 = encQ(qp[0], qp[1], qp[2], h);
    const s16x8 aq1 = encQ(qp[96], qp[97], qp[98], h);

    f32x16 zerov;
#pragma unroll
    for (int i = 0; i < 16; ++i) zerov[i] = 0.0f;

    float mn0 = 3.4e38f, mn1 = 3.4e38f;

    __syncthreads();

#define FOLD16(mn, a) { \
        float u0 = MIN3(a[0], a[1], a[2]); \
        float u1 = MIN3(a[3], a[4], a[5]); \
        float u2 = MIN3(a[6], a[7], a[8]); \
        float u3 = MIN3(a[9], a[10], a[11]); \
        float u4 = MIN3(a[12], a[13], a[14]); \
        float v0 = MIN3(u0, u1, u2); \
        float v1 = MIN3(u3, u4, a[15]); \
        (mn) = MIN3(v0, v1, (mn)); \
    }

    for (int rep = 0; rep < REP; ++rep) {
#pragma unroll 4
        for (int t = 0; t < 16; ++t) {
            const s16x8 d = sdb[t * 64 + lane];
            {
                f32x16 a0 = __builtin_amdgcn_mfma_f32_32x32x16_bf16(d, aq0, zerov, 0, 0, 0);
                FOLD16(mn0, a0);
            }
            {
                f32x16 a1 = __builtin_amdgcn_mfma_f32_32x32x16_bf16(d, aq1, zerov, 0, 0, 0);
                FOLD16(mn1, a1);
            }
        }
        // keep rep-2 live: opaque mins + memory clobber defeats LDS-load CSE
        asm volatile("" : "+v"(mn0), "+v"(mn1) :: "memory");
    }

    mn0 = fmaxf(fminf(mn0, __shfl_xor(mn0, 32)), 0.0f);
    mn1 = fmaxf(fminf(mn1, __shfl_xor(mn1, 32)), 0.0f);

    if (lane < 32) {
        const size_t qb = ((size_t)b << 13) + (size_t)tq * 32 + lane;
        atomicMin(&mout[qb],      __float_as_uint(mn0));
        atomicMin(&mout[qb + 32], __float_as_uint(mn1));
    }
}

// ---------------------------------------------------------------------------
// reduce + writeout: fixed-point u64 accumulation (order-independent ->
// deterministic); last-ticket block writes the scalar.
// ---------------------------------------------------------------------------
#define FIXSCALE 1099511627776.0   // 2^40
#define RBLOCKS 64

__global__ void __launch_bounds__(256) reduce_writeout(
    const unsigned* __restrict__ mall, unsigned long long* __restrict__ acc,
    unsigned* __restrict__ ticket, float* __restrict__ out)
{
    float s = 0.0f;
    for (int i = blockIdx.x * 256 + threadIdx.x; i < 65536; i += RBLOCKS * 256)
        s += sqrtf(__uint_as_float(mall[i]));
    for (int off = 32; off; off >>= 1) s += __shfl_down(s, off, 64);
    __shared__ float ws[4];
    if ((threadIdx.x & 63) == 0) ws[threadIdx.x >> 6] = s;
    __syncthreads();
    if (threadIdx.x == 0) {
        const double t = (double)(ws[0] + ws[1] + ws[2] + ws[3]) * (1.0 / 32768.0);
        atomicAdd(acc, (unsigned long long)(t * FIXSCALE));
        __threadfence();
        const unsigned tk = atomicAdd(ticket, 1u);
        if (tk == RBLOCKS - 1) {
            const unsigned long long v = atomicAdd(acc, 0ull);
            out[0] = (float)((double)v * (1.0 / FIXSCALE));
        }
    }
}

// ---------------------------------------------------------------------------
extern "C" void kernel_launch(void* const* d_in, const int* in_sizes, int n_in,
                              void* d_out, int out_size, void* d_ws, size_t ws_size,
                              hipStream_t stream) {
    const float* pred   = (const float*)d_in[0];   // [4,8192,3]
    const float* target = (const float*)d_in[1];   // [4,8192,3]
    float* out = (float*)d_out;

    unsigned* m1 = (unsigned*)d_ws;                       // [32768] pred mins
    unsigned* m2 = m1 + 32768;                            // [32768] target mins
    unsigned long long* acc = (unsigned long long*)(m2 + 32768);
    unsigned* ticket = (unsigned*)(acc + 1);

    init_kernel<<<256, 256, 0, stream>>>(m1, acc, ticket);

    minpass<<<4096, 256, 0, stream>>>(pred, target, m1, m2);

    reduce_writeout<<<RBLOCKS, 256, 0, stream>>>(m1, acc, ticket, out);
}

// Round 7
// 32.455 us; speedup vs baseline: 1.8150x; 1.8150x over previous
//
#include <hip/hip_runtime.h>

typedef short s16x8 __attribute__((ext_vector_type(8)));
typedef float f32x16 __attribute__((ext_vector_type(16)));

// bf16 round-to-nearest-even helpers
__device__ __forceinline__ unsigned short rne(float f) {
    unsigned u = __float_as_uint(f);
    return (unsigned short)((u + 0x7fffu + ((u >> 16) & 1u)) >> 16);
}
__device__ __forceinline__ float b2f(unsigned short b) {
    return __uint_as_float(((unsigned)b) << 16);
}

// MFMA forced into VGPRs: "=&v" early-clobber keeps dst disjoint from srcs,
// and "v" class forbids AGPR allocation (kills v_accvgpr_read/write traffic
// that round-6 counters exposed: VGPR_Count=24, VALUBusy 92%, MfmaUtil 26%).
__device__ __forceinline__ f32x16 mfma_v(s16x8 a, s16x8 b, f32x16 c) {
    f32x16 d;
    asm volatile("v_mfma_f32_32x32x16_bf16 %0, %1, %2, %3"
                 : "=&v"(d) : "v"(a), "v"(b), "v"(c));
    return d;
}

// guaranteed 3-input min (8 ops per 16-value fold)
#define VMIN3(d, a, b, c) \
    asm("v_min3_f32 %0, %1, %2, %3" : "=v"(d) : "v"(a), "v"(b), "v"(c))

#define FOLD16(mn, A) { \
        float u0, u1, u2, u3, u4, v0, v1; \
        VMIN3(u0, A[0],  A[1],  A[2]); \
        VMIN3(u1, A[3],  A[4],  A[5]); \
        VMIN3(u2, A[6],  A[7],  A[8]); \
        VMIN3(u3, A[9],  A[10], A[11]); \
        VMIN3(u4, A[12], A[13], A[14]); \
        VMIN3(v0, u0, u1, u2); \
        VMIN3(v1, u3, u4, A[15]); \
        VMIN3(mn, v0, v1, mn); \
    }

// 16-slot hi/lo-split encoding (validated rounds 4-6, absmax 0):
//   d2 = |q|^2 + |t|^2 - 2 (qh+ql).(th+tl)
// Q: lo=[hx,hy,hz,lx,ly,lz,hx,hy]  hi=[hz,nh,nl,1,1,lx,ly,lz]
// D: lo=[-2hx,-2hy,-2hz,-2hx,-2hy,-2hz,-2lx,-2ly] hi=[-2lz,1,1,nh,nl,-2lx,-2ly,-2lz]
__device__ __forceinline__ void encD(float x, float y, float z, s16x8& lo, s16x8& hi) {
    const unsigned short hx = rne(x), hy = rne(y), hz = rne(z);
    const float fx = b2f(hx), fy = b2f(hy), fz = b2f(hz);
    const unsigned short lx = rne(x - fx), ly = rne(y - fy), lz = rne(z - fz);
    const float n = fmaf(x, x, fmaf(y, y, z * z));
    const unsigned short nh = rne(n), nl = rne(n - b2f(nh));
    const unsigned short m2hx = rne(-2.f * fx), m2hy = rne(-2.f * fy), m2hz = rne(-2.f * fz);
    const unsigned short m2lx = rne(-2.f * b2f(lx)), m2ly = rne(-2.f * b2f(ly)), m2lz = rne(-2.f * b2f(lz));
    lo[0]=(short)m2hx; lo[1]=(short)m2hy; lo[2]=(short)m2hz; lo[3]=(short)m2hx;
    lo[4]=(short)m2hy; lo[5]=(short)m2hz; lo[6]=(short)m2lx; lo[7]=(short)m2ly;
    hi[0]=(short)m2lz; hi[1]=(short)0x3f80; hi[2]=(short)0x3f80; hi[3]=(short)nh;
    hi[4]=(short)nl;   hi[5]=(short)m2lx;  hi[6]=(short)m2ly;   hi[7]=(short)m2lz;
}

__device__ __forceinline__ s16x8 encQ(float x, float y, float z, int h) {
    const unsigned short hx = rne(x), hy = rne(y), hz = rne(z);
    const float fx = b2f(hx), fy = b2f(hy), fz = b2f(hz);
    const unsigned short lx = rne(x - fx), ly = rne(y - fy), lz = rne(z - fz);
    const float n = fmaf(x, x, fmaf(y, y, z * z));
    const unsigned short nh = rne(n), nl = rne(n - b2f(nh));
    s16x8 lo, hiV;
    lo[0]=(short)hx; lo[1]=(short)hy; lo[2]=(short)hz; lo[3]=(short)lx;
    lo[4]=(short)ly; lo[5]=(short)lz; lo[6]=(short)hx; lo[7]=(short)hy;
    hiV[0]=(short)hz; hiV[1]=(short)nh; hiV[2]=(short)nl; hiV[3]=(short)0x3f80;
    hiV[4]=(short)0x3f80; hiV[5]=(short)lx; hiV[6]=(short)ly; hiV[7]=(short)lz;
    return h ? hiV : lo;
}

// ---------------------------------------------------------------------------
__global__ void __launch_bounds__(256) init_kernel(
    unsigned* __restrict__ mb, unsigned long long* __restrict__ acc,
    unsigned* __restrict__ ticket)
{
    const int i = blockIdx.x * 256 + threadIdx.x;
    mb[i] = 0x7f800000u;   // +inf
    if (i == 0) { *acc = 0ull; *ticket = 0u; }
}

// ---------------------------------------------------------------------------
// minpass: bid fields qg(32) | split(16) | b(4) | pass(2).
// Software-pipelined: fold tile t's VGPR-resident MFMA results while issuing
// tile t+1. sched_barrier(0) fences pin the schedule so every fold executes
// >=24 cyc after its MFMA issue (16-pass MFMA -> ~18 SW wait states).
// ---------------------------------------------------------------------------
__global__ void __launch_bounds__(256) minpass(
    const float* __restrict__ pred, const float* __restrict__ tgt,
    unsigned* __restrict__ m1, unsigned* __restrict__ m2)
{
    __shared__ s16x8 sdb[16 * 64];   // [tile][half*32+pt], 16 KiB

    const int bid = blockIdx.x;
    const int qg = bid & 31, split = (bid >> 5) & 15, b = (bid >> 9) & 3, pass = bid >> 11;
    const float* __restrict__ q  = pass ? tgt : pred;
    const float* __restrict__ db = pass ? pred : tgt;
    unsigned* __restrict__ mout = pass ? m2 : m1;

    const int tid = threadIdx.x, lane = tid & 63, wid = tid >> 6;

    // stage & encode db chunk: points tid and tid+256
    {
        const float* dp = db + ((size_t)b * 8192 + split * 512 + tid) * 3;
        s16x8 lo, hi;
        encD(dp[0], dp[1], dp[2], lo, hi);
        sdb[(tid >> 5) * 64 + (tid & 31)] = lo;
        sdb[(tid >> 5) * 64 + 32 + (tid & 31)] = hi;
        const float* dp2 = dp + 768;
        encD(dp2[0], dp2[1], dp2[2], lo, hi);
        const int p = tid + 256;
        sdb[(p >> 5) * 64 + (p & 31)] = lo;
        sdb[(p >> 5) * 64 + 32 + (p & 31)] = hi;
    }

    // query fragments: 2 tiles per wave, encoded in-register
    const int tq = qg * 8 + wid * 2;
    const int h = lane >> 5;
    const float* qp = q + ((size_t)b * 8192 + tq * 32 + (lane & 31)) * 3;
    const s16x8 aq0 = encQ(qp[0], qp[1], qp[2], h);
    const s16x8 aq1 = encQ(qp[96], qp[97], qp[98], h);

    f32x16 zerov;
#pragma unroll
    for (int i = 0; i < 16; ++i) zerov[i] = 0.0f;

    float mn0 = 3.4e38f, mn1 = 3.4e38f;

    __syncthreads();

    f32x16 A0, A1, B0, B1;
    // prologue: issue tiles 0 (A) and 1 (B)
    {
        const s16x8 d0 = sdb[lane];
        A0 = mfma_v(d0, aq0, zerov);
        A1 = mfma_v(d0, aq1, zerov);
        const s16x8 d1 = sdb[64 + lane];
        B0 = mfma_v(d1, aq0, zerov);
        B1 = mfma_v(d1, aq1, zerov);
    }
    asm volatile("s_nop 7");   // pad first fold >= 24 cyc after A-issue

#pragma unroll
    for (int t = 0; t < 16; t += 2) {
        __builtin_amdgcn_sched_barrier(0);
        FOLD16(mn0, A0);
        FOLD16(mn1, A1);
        if (t + 2 < 16) {
            const s16x8 d = sdb[(t + 2) * 64 + lane];
            A0 = mfma_v(d, aq0, zerov);
            A1 = mfma_v(d, aq1, zerov);
        }
        __builtin_amdgcn_sched_barrier(0);
        FOLD16(mn0, B0);
        FOLD16(mn1, B1);
        if (t + 3 < 16) {
            const s16x8 d = sdb[(t + 3) * 64 + lane];
            B0 = mfma_v(d, aq0, zerov);
            B1 = mfma_v(d, aq1, zerov);
        }
    }
    __builtin_amdgcn_sched_barrier(0);

    mn0 = fmaxf(fminf(mn0, __shfl_xor(mn0, 32)), 0.0f);
    mn1 = fmaxf(fminf(mn1, __shfl_xor(mn1, 32)), 0.0f);

    if (lane < 32) {
        const size_t qb = ((size_t)b << 13) + (size_t)tq * 32 + lane;
        atomicMin(&mout[qb],      __float_as_uint(mn0));
        atomicMin(&mout[qb + 32], __float_as_uint(mn1));
    }
}

// ---------------------------------------------------------------------------
// reduce + writeout: fixed-point u64 accumulation (order-independent ->
// deterministic); last-ticket block writes the scalar.
// ---------------------------------------------------------------------------
#define FIXSCALE 1099511627776.0   // 2^40
#define RBLOCKS 64

__global__ void __launch_bounds__(256) reduce_writeout(
    const unsigned* __restrict__ mall, unsigned long long* __restrict__ acc,
    unsigned* __restrict__ ticket, float* __restrict__ out)
{
    float s = 0.0f;
    for (int i = blockIdx.x * 256 + threadIdx.x; i < 65536; i += RBLOCKS * 256)
        s += sqrtf(__uint_as_float(mall[i]));
    for (int off = 32; off; off >>= 1) s += __shfl_down(s, off, 64);
    __shared__ float ws[4];
    if ((threadIdx.x & 63) == 0) ws[threadIdx.x >> 6] = s;
    __syncthreads();
    if (threadIdx.x == 0) {
        const double t = (double)(ws[0] + ws[1] + ws[2] + ws[3]) * (1.0 / 32768.0);
        atomicAdd(acc, (unsigned long long)(t * FIXSCALE));
        __threadfence();
        const unsigned tk = atomicAdd(ticket, 1u);
        if (tk == RBLOCKS - 1) {
            const unsigned long long v = atomicAdd(acc, 0ull);
            out[0] = (float)((double)v * (1.0 / FIXSCALE));
        }
    }
}

// ---------------------------------------------------------------------------
extern "C" void kernel_launch(void* const* d_in, const int* in_sizes, int n_in,
                              void* d_out, int out_size, void* d_ws, size_t ws_size,
                              hipStream_t stream) {
    const float* pred   = (const float*)d_in[0];   // [4,8192,3]
    const float* target = (const float*)d_in[1];   // [4,8192,3]
    float* out = (float*)d_out;

    unsigned* m1 = (unsigned*)d_ws;                       // [32768] pred mins
    unsigned* m2 = m1 + 32768;                            // [32768] target mins
    unsigned long long* acc = (unsigned long long*)(m2 + 32768);
    unsigned* ticket = (unsigned*)(acc + 1);

    init_kernel<<<256, 256, 0, stream>>>(m1, acc, ticket);

    minpass<<<4096, 256, 0, stream>>>(pred, target, m1, m2);

    reduce_writeout<<<RBLOCKS, 256, 0, stream>>>(m1, acc, ticket, out);
}

// Round 8
// 30.058 us; speedup vs baseline: 1.9597x; 1.0797x over previous
//
#include <hip/hip_runtime.h>

typedef short s16x8 __attribute__((ext_vector_type(8)));
typedef float f32x16 __attribute__((ext_vector_type(16)));

// MFMA forced into VGPRs ("v" forbids AGPR; "=&v" keeps dst disjoint).
__device__ __forceinline__ f32x16 mfma_v(s16x8 a, s16x8 b, f32x16 c) {
    f32x16 d;
    asm volatile("v_mfma_f32_32x32x16_bf16 %0, %1, %2, %3"
                 : "=&v"(d) : "v"(a), "v"(b), "v"(c));
    return d;
}

#define VMIN3(d, a, b, c) \
    asm("v_min3_f32 %0, %1, %2, %3" : "=v"(d) : "v"(a), "v"(b), "v"(c))

#define FOLD16(mn, A) { \
        float u0, u1, u2, u3, u4, v0, v1; \
        VMIN3(u0, A[0],  A[1],  A[2]); \
        VMIN3(u1, A[3],  A[4],  A[5]); \
        VMIN3(u2, A[6],  A[7],  A[8]); \
        VMIN3(u3, A[9],  A[10], A[11]); \
        VMIN3(u4, A[12], A[13], A[14]); \
        VMIN3(v0, u0, u1, u2); \
        VMIN3(v1, u3, u4, A[15]); \
        VMIN3(mn, v0, v1, mn); \
    }

// bf16 round-to-nearest-even helpers
__device__ __forceinline__ unsigned short rne(float f) {
    unsigned u = __float_as_uint(f);
    return (unsigned short)((u + 0x7fffu + ((u >> 16) & 1u)) >> 16);
}
__device__ __forceinline__ float b2f(unsigned short b) {
    return __uint_as_float(((unsigned)b) << 16);
}

// 16-slot hi/lo-split encoding (validated rounds 4-7, absmax 0):
//   d2 = |q|^2 + |t|^2 - 2 (qh+ql).(th+tl)
__device__ __forceinline__ void encD(float x, float y, float z, s16x8& lo, s16x8& hi) {
    const unsigned short hx = rne(x), hy = rne(y), hz = rne(z);
    const float fx = b2f(hx), fy = b2f(hy), fz = b2f(hz);
    const unsigned short lx = rne(x - fx), ly = rne(y - fy), lz = rne(z - fz);
    const float n = fmaf(x, x, fmaf(y, y, z * z));
    const unsigned short nh = rne(n), nl = rne(n - b2f(nh));
    const unsigned short m2hx = rne(-2.f * fx), m2hy = rne(-2.f * fy), m2hz = rne(-2.f * fz);
    const unsigned short m2lx = rne(-2.f * b2f(lx)), m2ly = rne(-2.f * b2f(ly)), m2lz = rne(-2.f * b2f(lz));
    lo[0]=(short)m2hx; lo[1]=(short)m2hy; lo[2]=(short)m2hz; lo[3]=(short)m2hx;
    lo[4]=(short)m2hy; lo[5]=(short)m2hz; lo[6]=(short)m2lx; lo[7]=(short)m2ly;
    hi[0]=(short)m2lz; hi[1]=(short)0x3f80; hi[2]=(short)0x3f80; hi[3]=(short)nh;
    hi[4]=(short)nl;   hi[5]=(short)m2lx;  hi[6]=(short)m2ly;   hi[7]=(short)m2lz;
}

__device__ __forceinline__ s16x8 encQ(float x, float y, float z, int h) {
    const unsigned short hx = rne(x), hy = rne(y), hz = rne(z);
    const float fx = b2f(hx), fy = b2f(hy), fz = b2f(hz);
    const unsigned short lx = rne(x - fx), ly = rne(y - fy), lz = rne(z - fz);
    const float n = fmaf(x, x, fmaf(y, y, z * z));
    const unsigned short nh = rne(n), nl = rne(n - b2f(nh));
    s16x8 lo, hiV;
    lo[0]=(short)hx; lo[1]=(short)hy; lo[2]=(short)hz; lo[3]=(short)lx;
    lo[4]=(short)ly; lo[5]=(short)lz; lo[6]=(short)hx; lo[7]=(short)hy;
    hiV[0]=(short)hz; hiV[1]=(short)nh; hiV[2]=(short)nl; hiV[3]=(short)0x3f80;
    hiV[4]=(short)0x3f80; hiV[5]=(short)lx; hiV[6]=(short)ly; hiV[7]=(short)lz;
    return h ? hiV : lo;
}

// ---------------------------------------------------------------------------
// minpass: bid fields qg(32) | split(16) | b(4) | pass(2).
// 2-stage register pipeline: iteration t folds tiles {t,t+1} (MFMAs issued a
// full iteration earlier), issues MFMAs for tiles {t+2,t+3} (ds_reads issued
// a full iteration earlier), and prefetches ds_reads for tiles {t+4,t+5}.
// Every ds_read thus has ~150 issue-cycles before its MFMA consumes it, and
// every MFMA result ~150 cycles before its fold -- no lgkm/hazard stalls
// inside the sched_barrier-pinned phases (the round-7 mistake).
// No atomics: each block writes its per-split partial min to part[split][q].
// Block 0 zeroes acc/ticket for the downstream reduce (stream-ordered).
// ---------------------------------------------------------------------------
__global__ void __launch_bounds__(256) minpass(
    const float* __restrict__ pred, const float* __restrict__ tgt,
    float* __restrict__ part, unsigned long long* __restrict__ acc,
    unsigned* __restrict__ ticket)
{
    __shared__ s16x8 sdb[16 * 64];   // [tile][half*32+pt], 16 KiB

    const int bid = blockIdx.x;
    const int qg = bid & 31, split = (bid >> 5) & 15, b = (bid >> 9) & 3, pass = bid >> 11;
    const float* __restrict__ q  = pass ? tgt : pred;
    const float* __restrict__ db = pass ? pred : tgt;

    const int tid = threadIdx.x, lane = tid & 63, wid = tid >> 6;

    if (bid == 0 && tid == 0) { *acc = 0ull; *ticket = 0u; }

    // stage & encode db chunk: points tid and tid+256
    {
        const float* dp = db + ((size_t)b * 8192 + split * 512 + tid) * 3;
        s16x8 lo, hi;
        encD(dp[0], dp[1], dp[2], lo, hi);
        sdb[(tid >> 5) * 64 + (tid & 31)] = lo;
        sdb[(tid >> 5) * 64 + 32 + (tid & 31)] = hi;
        const float* dp2 = dp + 768;
        encD(dp2[0], dp2[1], dp2[2], lo, hi);
        const int p = tid + 256;
        sdb[(p >> 5) * 64 + (p & 31)] = lo;
        sdb[(p >> 5) * 64 + 32 + (p & 31)] = hi;
    }

    // query fragments: 2 tiles per wave, encoded in-register
    const int tq = qg * 8 + wid * 2;
    const int h = lane >> 5;
    const float* qp = q + ((size_t)b * 8192 + tq * 32 + (lane & 31)) * 3;
    const s16x8 aq0 = encQ(qp[0], qp[1], qp[2], h);
    const s16x8 aq1 = encQ(qp[96], qp[97], qp[98], h);

    f32x16 zerov;
#pragma unroll
    for (int i = 0; i < 16; ++i) zerov[i] = 0.0f;

    float mn0 = 3.4e38f, mn1 = 3.4e38f;

    __syncthreads();

    // prologue: tiles 0,1 loaded+issued; tiles 2,3 loaded
    s16x8 dA = sdb[lane];
    s16x8 dB = sdb[64 + lane];
    f32x16 A0 = mfma_v(dA, aq0, zerov);
    f32x16 A1 = mfma_v(dA, aq1, zerov);
    f32x16 B0 = mfma_v(dB, aq0, zerov);
    f32x16 B1 = mfma_v(dB, aq1, zerov);
    dA = sdb[2 * 64 + lane];
    dB = sdb[3 * 64 + lane];
    asm volatile("s_nop 7");

#pragma unroll
    for (int t = 0; t < 16; t += 2) {
        __builtin_amdgcn_sched_barrier(0);
        // phase A: prefetch t+4, fold tile t, issue tile t+2
        s16x8 dnA = dA;
        if (t + 4 < 16) dnA = sdb[(t + 4) * 64 + lane];
        FOLD16(mn0, A0);
        FOLD16(mn1, A1);
        if (t + 2 < 16) {
            A0 = mfma_v(dA, aq0, zerov);
            A1 = mfma_v(dA, aq1, zerov);
        }
        dA = dnA;
        __builtin_amdgcn_sched_barrier(0);
        // phase B: prefetch t+5, fold tile t+1, issue tile t+3
        s16x8 dnB = dB;
        if (t + 5 < 16) dnB = sdb[(t + 5) * 64 + lane];
        FOLD16(mn0, B0);
        FOLD16(mn1, B1);
        if (t + 3 < 16) {
            B0 = mfma_v(dB, aq0, zerov);
            B1 = mfma_v(dB, aq1, zerov);
        }
        dB = dnB;
    }
    __builtin_amdgcn_sched_barrier(0);

    mn0 = fmaxf(fminf(mn0, __shfl_xor(mn0, 32)), 0.0f);
    mn1 = fmaxf(fminf(mn1, __shfl_xor(mn1, 32)), 0.0f);

    if (lane < 32) {
        const size_t qi = ((size_t)pass << 15) + ((size_t)b << 13) + (size_t)tq * 32 + lane;
        part[(size_t)split * 65536 + qi]      = mn0;
        part[(size_t)split * 65536 + qi + 32] = mn1;
    }
}

// ---------------------------------------------------------------------------
// reduce + writeout: fold 16 split-partials per query (coalesced), sqrt, sum
// via fixed-point u64 (order-independent -> deterministic); last-ticket block
// writes the scalar.
// ---------------------------------------------------------------------------
#define FIXSCALE 1099511627776.0   // 2^40
#define RBLOCKS 64

__global__ void __launch_bounds__(256) reduce_writeout(
    const float* __restrict__ part, unsigned long long* __restrict__ acc,
    unsigned* __restrict__ ticket, float* __restrict__ out)
{
    const int q0 = blockIdx.x * 1024 + threadIdx.x;
    float s = 0.0f;
#pragma unroll
    for (int k = 0; k < 4; ++k) {
        const int qi = q0 + k * 256;
        float v = part[qi];
#pragma unroll
        for (int sp = 1; sp < 16; ++sp) v = fminf(v, part[(size_t)sp * 65536 + qi]);
        s += sqrtf(v);
    }
    for (int off = 32; off; off >>= 1) s += __shfl_down(s, off, 64);
    __shared__ float ws[4];
    if ((threadIdx.x & 63) == 0) ws[threadIdx.x >> 6] = s;
    __syncthreads();
    if (threadIdx.x == 0) {
        const double t = (double)(ws[0] + ws[1] + ws[2] + ws[3]) * (1.0 / 32768.0);
        atomicAdd(acc, (unsigned long long)(t * FIXSCALE));
        __threadfence();
        const unsigned tk = atomicAdd(ticket, 1u);
        if (tk == RBLOCKS - 1) {
            const unsigned long long v = atomicAdd(acc, 0ull);
            out[0] = (float)((double)v * (1.0 / FIXSCALE));
        }
    }
}

// ---------------------------------------------------------------------------
extern "C" void kernel_launch(void* const* d_in, const int* in_sizes, int n_in,
                              void* d_out, int out_size, void* d_ws, size_t ws_size,
                              hipStream_t stream) {
    const float* pred   = (const float*)d_in[0];   // [4,8192,3]
    const float* target = (const float*)d_in[1];   // [4,8192,3]
    float* out = (float*)d_out;

    float* part = (float*)d_ws;                              // [16][65536] = 4 MiB
    unsigned long long* acc = (unsigned long long*)((char*)d_ws + (size_t)16 * 65536 * 4);
    unsigned* ticket = (unsigned*)(acc + 1);

    minpass<<<4096, 256, 0, stream>>>(pred, target, part, acc, ticket);

    reduce_writeout<<<RBLOCKS, 256, 0, stream>>>(part, acc, ticket, out);
}